// Round 1
// baseline (96.054 us; speedup 1.0000x reference)
//
#include <hip/hip_runtime.h>

#define NPTS   8192      // data points
#define GSIZE  16384     // 128*128 grid
#define TS     1024      // tile size (points) staged in LDS
#define NTILES (NPTS / TS)
#define GPB    16        // grid points per block
#define NSEG   16        // segment-threads per grid point

__global__ __launch_bounds__(256, 4) void convcnp_encoder_kernel(
    const float* __restrict__ X,
    const float* __restrict__ Y,
    float* __restrict__ out)
{
    __shared__ float4 tile[TS];   // {x0, x1, y0, y1} per point, 16 KB

    const int tid = threadIdx.x;
    const int g   = tid >> 4;     // 0..15 : which grid point in this block
    const int seg = tid & 15;     // 0..15 : which n-segment

    const int gi = blockIdx.x * GPB + g;   // flat grid index, = ix*128 + iy
    const int ix = gi >> 7;
    const int iy = gi & 127;
    const float gx = -2.0f + (float)ix * (4.0f / 127.0f);
    const float gy = -2.0f + (float)iy * (4.0f / 127.0f);

    float s0 = 0.0f, s1 = 0.0f, s2 = 0.0f;

    const float4* X4 = (const float4*)X;   // 2 points per float4
    const float4* Y4 = (const float4*)Y;

    for (int t = 0; t < NTILES; ++t) {
        // --- stage TS points of X and Y into LDS, interleaved ---
        #pragma unroll
        for (int i = 0; i < TS / 2; i += 256) {
            float4 xa = X4[t * (TS / 2) + i + tid];
            float4 ya = Y4[t * (TS / 2) + i + tid];
            int p = 2 * (i + tid);
            tile[p]     = make_float4(xa.x, xa.y, ya.x, ya.y);
            tile[p + 1] = make_float4(xa.z, xa.w, ya.z, ya.w);
        }
        __syncthreads();

        // --- each thread: TS/NSEG pairs, stride NSEG so all threads stay hot ---
        #pragma unroll 8
        for (int j = 0; j < TS / NSEG; ++j) {
            float4 p = tile[j * NSEG + seg];
            float dx = gx - p.x;
            float dy = gy - p.y;
            float d2 = dx * dx + dy * dy;
            float k  = __expf(-0.5f * d2);   // v_mul + v_exp_f32
            s0 += k;
            s1 += k * p.z;
            s2 += k * p.w;
        }
        __syncthreads();
    }

    // --- reduce the 16 segment partials (contiguous 16-lane groups) ---
    #pragma unroll
    for (int off = 8; off >= 1; off >>= 1) {
        s0 += __shfl_down(s0, off, 16);
        s1 += __shfl_down(s1, off, 16);
        s2 += __shfl_down(s2, off, 16);
    }

    if (seg == 0) {
        // output layout: (3, n_y, n_x) -> out[c*16384 + iy*128 + ix]
        const int o = iy * 128 + ix;
        float inv = 1.0f / s0;          // s0 = denom = Gram @ ones
        out[0 * GSIZE + o] = s0;        // fm[:,0] is NOT divided by denom
        out[1 * GSIZE + o] = s1 * inv;
        out[2 * GSIZE + o] = s2 * inv;
    }
}

extern "C" void kernel_launch(void* const* d_in, const int* in_sizes, int n_in,
                              void* d_out, int out_size, void* d_ws, size_t ws_size,
                              hipStream_t stream) {
    const float* X = (const float*)d_in[0];
    const float* Y = (const float*)d_in[1];
    float* out = (float*)d_out;
    convcnp_encoder_kernel<<<GSIZE / GPB, 256, 0, stream>>>(X, Y, out);
}

// Round 2
// 84.286 us; speedup vs baseline: 1.1396x; 1.1396x over previous
//
#include <hip/hip_runtime.h>

#define NPTS   8192                 // data points
#define GSIZE  16384                // 128*128 grid
#define NSEG   64                   // point segments (split across blocks)
#define SEGPTS (NPTS / NSEG)        // 128 points per segment
#define GPB    1024                 // grid points per block
#define GPT    4                    // grid points per thread (registers)
#define NGB    (GSIZE / GPB)        // 16 grid-blocks
#define L2E    1.4426950408889634f  // log2(e)
#define WS_NEEDED ((size_t)NSEG * 3 * GSIZE * sizeof(float))  // 12.6 MB

// ---------------- K1: partial sums over one point-segment -------------------
// exp(-0.5||g-x||^2) = e^{bg} * exp2( L2E*(bx + g.x) ),  bx = -0.5||x||^2.
// e^{bg} is per-grid-point and applied in K2 (cancels in channels 1,2).
__global__ __launch_bounds__(256, 4) void convcnp_k1(
    const float* __restrict__ X,
    const float* __restrict__ Y,
    float* __restrict__ ws)
{
    __shared__ float4 P[SEGPTS];   // {x0*L2E, x1*L2E, bx*L2E, y0}
    __shared__ float  Q[SEGPTS];   // {y1}

    const int tid = threadIdx.x;
    const int gb  = blockIdx.x & (NGB - 1);   // 0..15 grid-block
    const int seg = blockIdx.x >> 4;          // 0..63 point-segment

    if (tid < SEGPTS) {
        int j = seg * SEGPTS + tid;
        float2 x = ((const float2*)X)[j];
        float2 y = ((const float2*)Y)[j];
        float bx = -0.5f * (x.x * x.x + x.y * x.y);
        P[tid] = make_float4(x.x * L2E, x.y * L2E, bx * L2E, y.x);
        Q[tid] = y.y;
    }
    __syncthreads();

    float gx[GPT], gy[GPT];
    float s0[GPT], s1[GPT], s2[GPT];
    #pragma unroll
    for (int k = 0; k < GPT; ++k) {
        int gi = gb * GPB + k * 256 + tid;    // flat grid index = ix*128 + iy
        int ix = gi >> 7, iy = gi & 127;
        gx[k] = -2.0f + (float)ix * (4.0f / 127.0f);
        gy[k] = -2.0f + (float)iy * (4.0f / 127.0f);
        s0[k] = s1[k] = s2[k] = 0.0f;
    }

    #pragma unroll 4
    for (int j = 0; j < SEGPTS; ++j) {
        float4 p  = P[j];          // wave-uniform address -> LDS broadcast
        float  y1 = Q[j];
        #pragma unroll
        for (int k = 0; k < GPT; ++k) {
            float t = fmaf(gy[k], p.y, p.z);
            t       = fmaf(gx[k], p.x, t);
            float E = __builtin_amdgcn_exp2f(t);   // v_exp_f32
            s0[k] += E;
            s1[k] = fmaf(E, p.w, s1[k]);
            s2[k] = fmaf(E, y1, s2[k]);
        }
    }

    #pragma unroll
    for (int k = 0; k < GPT; ++k) {
        int gi = gb * GPB + k * 256 + tid;    // coalesced (stride = tid)
        ws[(seg * 3 + 0) * GSIZE + gi] = s0[k];
        ws[(seg * 3 + 1) * GSIZE + gi] = s1[k];
        ws[(seg * 3 + 2) * GSIZE + gi] = s2[k];
    }
}

// ---------------- K2: reduce segments, scale, divide, transpose-store -------
__global__ __launch_bounds__(256) void convcnp_k2(
    const float* __restrict__ ws,
    float* __restrict__ out)
{
    int g = blockIdx.x * 256 + threadIdx.x;   // 64 blocks
    float s0 = 0.0f, s1 = 0.0f, s2 = 0.0f;
    #pragma unroll 8
    for (int s = 0; s < NSEG; ++s) {          // coalesced reads (stride g)
        s0 += ws[(s * 3 + 0) * GSIZE + g];
        s1 += ws[(s * 3 + 1) * GSIZE + g];
        s2 += ws[(s * 3 + 2) * GSIZE + g];
    }
    int ix = g >> 7, iy = g & 127;
    float gx = -2.0f + (float)ix * (4.0f / 127.0f);
    float gy = -2.0f + (float)iy * (4.0f / 127.0f);
    float eg = __builtin_amdgcn_exp2f(-0.5f * L2E * (gx * gx + gy * gy));
    float inv = 1.0f / s0;
    int o = iy * 128 + ix;                    // (3, n_y, n_x) layout
    out[o]             = eg * s0;             // channel 0: denom, NOT divided
    out[GSIZE + o]     = s1 * inv;            // eg cancels in the ratio
    out[2 * GSIZE + o] = s2 * inv;
}

// ---------------- Fallback: proven R1 single-kernel (if ws too small) -------
#define TS    1024
#define NTILES (NPTS / TS)
__global__ __launch_bounds__(256, 4) void convcnp_fallback(
    const float* __restrict__ X,
    const float* __restrict__ Y,
    float* __restrict__ out)
{
    __shared__ float4 tile[TS];
    const int tid = threadIdx.x;
    const int g   = tid >> 4;
    const int sg  = tid & 15;
    const int gi = blockIdx.x * 16 + g;
    const int ix = gi >> 7;
    const int iy = gi & 127;
    const float gx = -2.0f + (float)ix * (4.0f / 127.0f);
    const float gy = -2.0f + (float)iy * (4.0f / 127.0f);
    float s0 = 0.0f, s1 = 0.0f, s2 = 0.0f;
    const float4* X4 = (const float4*)X;
    const float4* Y4 = (const float4*)Y;
    for (int t = 0; t < NTILES; ++t) {
        #pragma unroll
        for (int i = 0; i < TS / 2; i += 256) {
            float4 xa = X4[t * (TS / 2) + i + tid];
            float4 ya = Y4[t * (TS / 2) + i + tid];
            int p = 2 * (i + tid);
            tile[p]     = make_float4(xa.x, xa.y, ya.x, ya.y);
            tile[p + 1] = make_float4(xa.z, xa.w, ya.z, ya.w);
        }
        __syncthreads();
        #pragma unroll 8
        for (int j = 0; j < TS / 16; ++j) {
            float4 p = tile[j * 16 + sg];
            float dx = gx - p.x;
            float dy = gy - p.y;
            float d2 = dx * dx + dy * dy;
            float k  = __expf(-0.5f * d2);
            s0 += k; s1 += k * p.z; s2 += k * p.w;
        }
        __syncthreads();
    }
    #pragma unroll
    for (int off = 8; off >= 1; off >>= 1) {
        s0 += __shfl_down(s0, off, 16);
        s1 += __shfl_down(s1, off, 16);
        s2 += __shfl_down(s2, off, 16);
    }
    if (sg == 0) {
        const int o = iy * 128 + ix;
        float inv = 1.0f / s0;
        out[o]             = s0;
        out[GSIZE + o]     = s1 * inv;
        out[2 * GSIZE + o] = s2 * inv;
    }
}

extern "C" void kernel_launch(void* const* d_in, const int* in_sizes, int n_in,
                              void* d_out, int out_size, void* d_ws, size_t ws_size,
                              hipStream_t stream) {
    const float* X = (const float*)d_in[0];
    const float* Y = (const float*)d_in[1];
    float* out = (float*)d_out;
    if (ws_size >= WS_NEEDED) {
        float* ws = (float*)d_ws;
        convcnp_k1<<<NGB * NSEG, 256, 0, stream>>>(X, Y, ws);
        convcnp_k2<<<GSIZE / 256, 256, 0, stream>>>(ws, out);
    } else {
        convcnp_fallback<<<GSIZE / 16, 256, 0, stream>>>(X, Y, out);
    }
}